// Round 10
// baseline (15.650 us; speedup 1.0000x reference)
//
#include <hip/hip_runtime.h>

#define NJ 32
#define BLK 256

// ---- DPP-based segmented (32-lane) inclusive prefix scan (full-rate VALU).
template<int CTRL, int ROW, int BANK>
__device__ __forceinline__ float dpp0(float x) {
    return __int_as_float(
        __builtin_amdgcn_update_dpp(0, __float_as_int(x), CTRL, ROW, BANK, false));
}

__device__ __forceinline__ float scan32(float x) {
    x += dpp0<0x111, 0xf, 0xf>(x);   // row_shr:1
    x += dpp0<0x112, 0xf, 0xf>(x);   // row_shr:2
    x += dpp0<0x114, 0xf, 0xe>(x);   // row_shr:4
    x += dpp0<0x118, 0xf, 0xc>(x);   // row_shr:8
    x += dpp0<0x142, 0xa, 0xf>(x);   // row_bcast:15 -> rows 1,3
    return x;
}

// Shift whole wave down one lane (lane i <- lane i-1); wave lane 0 gets 0.
__device__ __forceinline__ float wave_shr1(float x) {
    return __int_as_float(
        __builtin_amdgcn_update_dpp(0, __float_as_int(x), 0x138, 0xf, 0xf, false));
}

// Broadcast lane 31 of each 32-lane group (ds_swizzle BitMode, lane'=31).
__device__ __forceinline__ float bcast31(float x) {
    return __int_as_float(
        __builtin_amdgcn_ds_swizzle(__float_as_int(x), 0x03E0));
}

// Native HW sincos: v_sin/v_cos take REVOLUTIONS; v_fract is the exact
// periodic reduction. 4 full/quarter-rate ops, no branches, no ocml call.
// (1/2pi is even an inline constant on the mul.)
__device__ __forceinline__ void fast_sincos(float x, float& s, float& c) {
    float r = __builtin_amdgcn_fractf(x * 0.15915494309189535f);
    s = __builtin_amdgcn_sinf(r);
    c = __builtin_amdgcn_cosf(r);
}

struct Consts {
    float m, mcx, mcy, i2z, px, py, damp;
};

// One batch row (32 joints across a 32-lane segment) -> tau for this lane.
__device__ __forceinline__ float tau_row(float qj, float qdj, float qddj,
                                         bool seg0, const Consts& C)
{
    // ---- Forward pass as prefix sums (world frame). ----
    float phi = scan32(qj);                     // phi_j
    float wI  = scan32(qdj);                    // w_j
    float aI  = scan32(qddj);                   // alpha_j
    float wP  = wI - qdj;                       // w_{j-1}
    float aP  = aI - qddj;                      // alpha_{j-1}

    float c, s;
    fast_sincos(phi, s, c);                     // at phi_j (native HW path)
    float cp = wave_shr1(c);                    // at phi_{j-1} (prev lane)
    float sp = wave_shr1(s);
    cp = seg0 ? 1.f : cp;
    sp = seg0 ? 0.f : sp;

    // d_j = Rz(phi_{j-1}) * p_j   (x,y only)
    float dx = cp*C.px - sp*C.py;
    float dy = sp*C.px + cp*C.py;

    // VL_j = sum_{k<=j} w_{k-1} * (-dy_k, dx_k)
    float VLx = scan32(-wP*dy);
    float VLy = scan32( wP*dx);

    // AL_j = sum_{k<=j} [ alpha_{k-1}*(-dy,dx) + qd_k*(VLy_k, -VLx_k) ]
    float ALx = scan32(fmaf(-aP, dy,  qdj*VLy));
    float ALy = scan32(fmaf( aP, dx, -qdj*VLx));

    // ---- Backward pass as suffix sums (world frame; z-chain only). ----
    float mcwx = c*C.mcx - s*C.mcy;             // Rz(phi_j) * mc
    float mcwy = s*C.mcx + c*C.mcy;

    // fv_l = m*VL + mc_w x (0,0,w)
    float fv_lx = fmaf(C.m, VLx,  wI*mcwy);
    float fv_ly = fmaf(C.m, VLy, -wI*mcwx);

    // local force terms: fa_l + (0,0,w) x fv_l   (x,y)
    float llx = fmaf(C.m, ALx, fmaf( aI, mcwy, -wI*fv_ly));
    float lly = fmaf(C.m, ALy, fmaf(-aI, mcwx,  wI*fv_lx));

    // F_j = suffix sum via segment total - prefix + x
    float Px = scan32(llx);
    float Py = scan32(lly);
    float Fx = bcast31(Px) - Px + llx;
    float Fy = bcast31(Py) - Py + lly;

    // z-moment chain: a_k = fa_az + (VL x fv_l)z ; b_k = (d x F)z
    float a = fmaf(aI, C.i2z, mcwx*ALy - mcwy*ALx + VLx*fv_ly - VLy*fv_lx);
    float b = dx*Fy - dy*Fx;
    float ab = a + b;
    float Pr = scan32(ab);
    float Nz = bcast31(Pr) - Pr + ab - b;       // suffix(a+b) - b

    return fmaf(C.damp, qdj, Nz);
}

__global__ __launch_bounds__(BLK, 4) void rnea_kernel(
    const float* __restrict__ q,
    const float* __restrict__ qd,
    const float* __restrict__ qdd,
    const float* __restrict__ trans,
    const float* __restrict__ mass,
    const float* __restrict__ com,
    const float* __restrict__ inertia,
    const float* __restrict__ damping,
    float* __restrict__ out,
    int Bn)
{
    const int t    = blockIdx.x * BLK + threadIdx.x;
    const int lane = threadIdx.x & 31;          // joint index
    const int half = Bn >> 1;
    const int r0   = t >> 5;                    // first batch row
    if (r0 >= half) return;
    const size_t i0 = (size_t)r0 * NJ + lane;   // coalesced
    const size_t i1 = i0 + (size_t)half * NJ;   // coalesced (second row block)

    // Issue all global loads first (latency overlap across both rows).
    float q0   = q  [i0], q1   = q  [i1];
    float qd0  = qd [i0], qd1  = qd [i1];
    float qdd0 = qdd[i0], qdd1 = qdd[i1];

    // Per-joint constants, gathered once, shared by both rows.
    Consts C;
    C.m    = mass[lane];
    float cx = com[3*lane+0], cy = com[3*lane+1];
    C.mcx  = C.m*cx;  C.mcy = C.m*cy;
    C.i2z  = fmaf(C.m, cx*cx + cy*cy, inertia[9*lane+8]);   // Ibar_zz
    C.px   = trans[3*lane+0];
    C.py   = trans[3*lane+1];
    C.damp = damping[lane];

    const bool seg0 = (lane == 0);

    float t0 = tau_row(q0, qd0, qdd0, seg0, C);
    float t1 = tau_row(q1, qd1, qdd1, seg0, C);

    out[i0] = t0;
    out[i1] = t1;
}

extern "C" void kernel_launch(void* const* d_in, const int* in_sizes, int n_in,
                              void* d_out, int out_size, void* d_ws, size_t ws_size,
                              hipStream_t stream) {
    const float* q       = (const float*)d_in[0];
    const float* qd      = (const float*)d_in[1];
    const float* qdd     = (const float*)d_in[2];
    const float* trans   = (const float*)d_in[3];
    const float* mass    = (const float*)d_in[4];
    const float* com     = (const float*)d_in[5];
    const float* inertia = (const float*)d_in[6];
    const float* damping = (const float*)d_in[7];
    float* out = (float*)d_out;

    int Bn = in_sizes[0] / NJ;
    long long threads = (long long)(Bn/2) * 32;
    int grid = (int)((threads + BLK - 1) / BLK);
    hipLaunchKernelGGL(rnea_kernel, dim3(grid), dim3(BLK), 0, stream,
                       q, qd, qdd, trans, mass, com, inertia, damping, out, Bn);
}

// Round 11
// 14.188 us; speedup vs baseline: 1.1030x; 1.1030x over previous
//
#include <hip/hip_runtime.h>

#define NJ 32
#define BLK 256

// ---- Minimal-form segmented (32-lane) inclusive prefix scans ----
// 5 x v_add_f32_dpp per scan, multiple independent chains interleaved in one
// asm block so dependent DPP ops are >=2 issue slots apart (gfx9-lineage
// VALU->DPP hazard). bound_ctrl:0 (asm convention: out-of-range reads 0) makes
// shifts add the scan identity; row_bcast:15 row_mask:0xa stitches 16->32.

#define MODS1 "row_shr:1 row_mask:0xf bank_mask:0xf bound_ctrl:0"
#define MODS2 "row_shr:2 row_mask:0xf bank_mask:0xf bound_ctrl:0"
#define MODS4 "row_shr:4 row_mask:0xf bank_mask:0xf bound_ctrl:0"
#define MODS8 "row_shr:8 row_mask:0xf bank_mask:0xf bound_ctrl:0"
#define MODSB "row_bcast:15 row_mask:0xa bank_mask:0xf"

#define STEP6(m) \
  "v_add_f32_dpp %0, %0, %0 " m "\n\t" \
  "v_add_f32_dpp %1, %1, %1 " m "\n\t" \
  "v_add_f32_dpp %2, %2, %2 " m "\n\t" \
  "v_add_f32_dpp %3, %3, %3 " m "\n\t" \
  "v_add_f32_dpp %4, %4, %4 " m "\n\t" \
  "v_add_f32_dpp %5, %5, %5 " m "\n\t"

#define STEP4(m) \
  "v_add_f32_dpp %0, %0, %0 " m "\n\t" \
  "v_add_f32_dpp %1, %1, %1 " m "\n\t" \
  "v_add_f32_dpp %2, %2, %2 " m "\n\t" \
  "v_add_f32_dpp %3, %3, %3 " m "\n\t"

#define STEP2(m) \
  "v_add_f32_dpp %0, %0, %0 " m "\n\t" \
  "v_add_f32_dpp %1, %1, %1 " m "\n\t" \
  "s_nop 0\n\t"

__device__ __forceinline__ void scan6(float& a, float& b, float& c,
                                      float& d, float& e, float& f) {
    asm("s_nop 1\n\t"
        STEP6(MODS1) STEP6(MODS2) STEP6(MODS4) STEP6(MODS8) STEP6(MODSB)
        : "+v"(a), "+v"(b), "+v"(c), "+v"(d), "+v"(e), "+v"(f));
}

__device__ __forceinline__ void scan4(float& a, float& b, float& c, float& d) {
    asm("s_nop 1\n\t"
        STEP4(MODS1) STEP4(MODS2) STEP4(MODS4) STEP4(MODS8) STEP4(MODSB)
        : "+v"(a), "+v"(b), "+v"(c), "+v"(d));
}

__device__ __forceinline__ void scan2(float& a, float& b) {
    asm("s_nop 1\n\t"
        STEP2(MODS1) STEP2(MODS2) STEP2(MODS4) STEP2(MODS8) STEP2(MODSB)
        : "+v"(a), "+v"(b));
}

// Segment totals after an inclusive scan live in lanes 31 / 63.
// VALU-only (v_readlane), no LDS pipe, ~order-of-magnitude lower latency
// than ds_swizzle+lgkmcnt(0).
__device__ __forceinline__ float seg_total(float x, int hiHalf) {
    int lo, hi;
    asm("s_nop 1\n\t"
        "v_readlane_b32 %0, %2, 31\n\t"
        "v_readlane_b32 %1, %2, 63"
        : "=s"(lo), "=s"(hi) : "v"(x));
    return __int_as_float(hiHalf ? hi : lo);
}

// Shift whole wave down one lane (lane i <- lane i-1); wave lane 0 gets 0.
__device__ __forceinline__ float wave_shr1(float x) {
    return __int_as_float(
        __builtin_amdgcn_update_dpp(0, __float_as_int(x), 0x138, 0xf, 0xf, false));
}

// Native HW sincos (revolutions + fract reduction), verified round 10.
__device__ __forceinline__ void fast_sincos(float x, float& s, float& c) {
    float r = __builtin_amdgcn_fractf(x * 0.15915494309189535f);
    s = __builtin_amdgcn_sinf(r);
    c = __builtin_amdgcn_cosf(r);
}

__global__ __launch_bounds__(BLK) void rnea_kernel(
    const float* __restrict__ q,
    const float* __restrict__ qd,
    const float* __restrict__ qdd,
    const float* __restrict__ trans,
    const float* __restrict__ mass,
    const float* __restrict__ com,
    const float* __restrict__ inertia,
    const float* __restrict__ damping,
    float* __restrict__ out,
    int Bn)
{
    const int t    = blockIdx.x * BLK + threadIdx.x;
    const int lane = threadIdx.x & 31;          // joint index
    const int hiH  = (threadIdx.x >> 5) & 1;    // which 32-lane segment
    const int half = Bn >> 1;
    const int r0   = t >> 5;
    if (r0 >= half) return;
    const size_t i0 = (size_t)r0 * NJ + lane;   // coalesced
    const size_t i1 = i0 + (size_t)half * NJ;   // coalesced

    // Issue all global loads up front.
    float q0   = q  [i0], q1   = q  [i1];
    float qd0  = qd [i0], qd1  = qd [i1];
    float qdd0 = qdd[i0], qdd1 = qdd[i1];

    // Per-joint constants (L1-hot broadcast lines), shared by both rows.
    float m    = mass[lane];
    float cx   = com[3*lane+0], cy = com[3*lane+1];
    float mcx  = m*cx, mcy = m*cy;
    float i2z  = fmaf(m, cx*cx + cy*cy, inertia[9*lane+8]);   // Ibar_zz
    float px   = trans[3*lane+0], py = trans[3*lane+1];
    float damp = damping[lane];
    const bool seg0 = (lane == 0);

    // ---- Stage A: 6 independent prefix scans (both rows' q, qd, qdd).
    float phi0 = q0, phi1 = q1, wI0 = qd0, wI1 = qd1, aI0 = qdd0, aI1 = qdd1;
    scan6(phi0, phi1, wI0, wI1, aI0, aI1);
    float wP0 = wI0 - qd0,  wP1 = wI1 - qd1;
    float aP0 = aI0 - qdd0, aP1 = aI1 - qdd1;

    float c0, s0, c1, s1;
    fast_sincos(phi0, s0, c0);
    fast_sincos(phi1, s1, c1);
    float cp0 = wave_shr1(c0), sp0 = wave_shr1(s0);
    float cp1 = wave_shr1(c1), sp1 = wave_shr1(s1);
    cp0 = seg0 ? 1.f : cp0;  sp0 = seg0 ? 0.f : sp0;
    cp1 = seg0 ? 1.f : cp1;  sp1 = seg0 ? 0.f : sp1;

    // d_j = Rz(phi_{j-1}) * p_j
    float dx0 = cp0*px - sp0*py, dy0 = sp0*px + cp0*py;
    float dx1 = cp1*px - sp1*py, dy1 = sp1*px + cp1*py;

    // ---- Stage B: VL scans (4 chains).
    float VLx0 = -wP0*dy0, VLy0 = wP0*dx0;
    float VLx1 = -wP1*dy1, VLy1 = wP1*dx1;
    scan4(VLx0, VLy0, VLx1, VLy1);

    // ---- Stage C: AL scans (4 chains).
    float ALx0 = fmaf(-aP0, dy0,  qd0*VLy0);
    float ALy0 = fmaf( aP0, dx0, -qd0*VLx0);
    float ALx1 = fmaf(-aP1, dy1,  qd1*VLy1);
    float ALy1 = fmaf( aP1, dx1, -qd1*VLx1);
    scan4(ALx0, ALy0, ALx1, ALy1);

    // ---- Backward (world frame, z-chain).
    float mcwx0 = c0*mcx - s0*mcy, mcwy0 = s0*mcx + c0*mcy;
    float mcwx1 = c1*mcx - s1*mcy, mcwy1 = s1*mcx + c1*mcy;

    float fv_lx0 = fmaf(m, VLx0,  wI0*mcwy0);
    float fv_ly0 = fmaf(m, VLy0, -wI0*mcwx0);
    float fv_lx1 = fmaf(m, VLx1,  wI1*mcwy1);
    float fv_ly1 = fmaf(m, VLy1, -wI1*mcwx1);

    float llx0 = fmaf(m, ALx0, fmaf( aI0, mcwy0, -wI0*fv_ly0));
    float lly0 = fmaf(m, ALy0, fmaf(-aI0, mcwx0,  wI0*fv_lx0));
    float llx1 = fmaf(m, ALx1, fmaf( aI1, mcwy1, -wI1*fv_ly1));
    float lly1 = fmaf(m, ALy1, fmaf(-aI1, mcwx1,  wI1*fv_lx1));

    // ---- Stage D: force prefix scans (4 chains), suffix via totals.
    float Px0 = llx0, Py0 = lly0, Px1 = llx1, Py1 = lly1;
    scan4(Px0, Py0, Px1, Py1);
    float Fx0 = seg_total(Px0, hiH) - Px0 + llx0;
    float Fy0 = seg_total(Py0, hiH) - Py0 + lly0;
    float Fx1 = seg_total(Px1, hiH) - Px1 + llx1;
    float Fy1 = seg_total(Py1, hiH) - Py1 + lly1;

    // ---- Stage E: z-moment chains (2 chains).
    float a0 = fmaf(aI0, i2z, mcwx0*ALy0 - mcwy0*ALx0 + VLx0*fv_ly0 - VLy0*fv_lx0);
    float a1 = fmaf(aI1, i2z, mcwx1*ALy1 - mcwy1*ALx1 + VLx1*fv_ly1 - VLy1*fv_lx1);
    float b0 = dx0*Fy0 - dy0*Fx0;
    float b1 = dx1*Fy1 - dy1*Fx1;
    float ab0 = a0 + b0, ab1 = a1 + b1;
    float Pr0 = ab0, Pr1 = ab1;
    scan2(Pr0, Pr1);
    float Nz0 = seg_total(Pr0, hiH) - Pr0 + ab0 - b0;
    float Nz1 = seg_total(Pr1, hiH) - Pr1 + ab1 - b1;

    out[i0] = fmaf(damp, qd0, Nz0);
    out[i1] = fmaf(damp, qd1, Nz1);
}

extern "C" void kernel_launch(void* const* d_in, const int* in_sizes, int n_in,
                              void* d_out, int out_size, void* d_ws, size_t ws_size,
                              hipStream_t stream) {
    const float* q       = (const float*)d_in[0];
    const float* qd      = (const float*)d_in[1];
    const float* qdd     = (const float*)d_in[2];
    const float* trans   = (const float*)d_in[3];
    const float* mass    = (const float*)d_in[4];
    const float* com     = (const float*)d_in[5];
    const float* inertia = (const float*)d_in[6];
    const float* damping = (const float*)d_in[7];
    float* out = (float*)d_out;

    int Bn = in_sizes[0] / NJ;
    long long threads = (long long)(Bn/2) * 32;
    int grid = (int)((threads + BLK - 1) / BLK);
    hipLaunchKernelGGL(rnea_kernel, dim3(grid), dim3(BLK), 0, stream,
                       q, qd, qdd, trans, mass, com, inertia, damping, out, Bn);
}